// Round 3
// baseline (377.894 us; speedup 1.0000x reference)
//
#include <hip/hip_runtime.h>
#include <hip/hip_bf16.h>

#define NPTS  64
#define NCOLS 500000
#define NANG  2016   // 64*63/2

typedef __attribute__((ext_vector_type(8))) short bf16x8;
typedef __attribute__((ext_vector_type(4))) float f32x4;

static __device__ inline short f2bf(float f) {
    union { float f; unsigned u; } uf; uf.f = f;
    unsigned u = uf.u;
    // round-to-nearest-even bf16
    unsigned r = (u + 0x7fffu + ((u >> 16) & 1u)) >> 16;
    return (short)r;
}

// ---------------------------------------------------------------------------
// Kernel 1: build M = diag(mus) * (R_{K-1} ... R_1 R_0)  (64x64 fp32 -> d_ws)
// One wave; lane = column of Q. Q lives in LDS (row-major, +1 pad ->
// conflict-free per-lane reads). The 2016-rotation chain keeps the current
// iTop row value in a register; LDS reads are double-buffered in chunks of 8
// so ds_read latency is off the dependent-FMA chain. Rolled loop => small
// code, no I-cache streaming (the round-2 93 us pathology).
// ---------------------------------------------------------------------------
__global__ __launch_bounds__(64) void build_M(const float* __restrict__ angles,
                                              const float* __restrict__ mus,
                                              float* __restrict__ Mout) {
    __shared__ float  Q[NPTS][NPTS + 1];
    __shared__ float2 CSN[NANG];          // packed {cos, sin} -> ds_read_b64
    const int tid = threadIdx.x;

    for (int k = tid; k < NANG; k += 64) {
        float a = angles[k];
        float s, c;
        sincosf(a, &s, &c);
        CSN[k] = make_float2(c, s);
    }
#pragma unroll
    for (int r0 = 0; r0 < NPTS; ++r0)
        Q[r0][tid] = (r0 == tid) ? 1.0f : 0.0f;
    __syncthreads();

    int k = 0;
    float r = Q[0][tid];                  // current iTop row value (this col)
    for (int i = 0; i < NPTS - 1; ++i) {
        int ib = i + 1;
        const int n = (NPTS - 1) - i;     // rotations this round
        // prefetch first chunk
        float  bb[8];
        float2 cs0[8];
        int cur = n < 8 ? n : 8;
#pragma unroll
        for (int j = 0; j < 8; ++j)
            if (j < cur) { bb[j] = Q[ib + j][tid]; cs0[j] = CSN[k + j]; }
        int done = 0;
        while (done < n) {
            int nxt = n - done - cur;
            if (nxt > 8) nxt = 8;
            float  b2[8];
            float2 cs2[8];
#pragma unroll
            for (int j = 0; j < 8; ++j)
                if (j < nxt) { b2[j] = Q[ib + cur + j][tid]; cs2[j] = CSN[k + cur + j]; }
#pragma unroll
            for (int j = 0; j < 8; ++j)
                if (j < cur) {
                    float c = cs0[j].x, s = cs0[j].y, b = bb[j];
                    Q[ib + j][tid] = s * r + c * b;   // uses OLD r (matches ref)
                    r = c * r - s * b;
                }
            ib += cur; k += cur; done += cur;
            cur = nxt;
#pragma unroll
            for (int j = 0; j < 8; ++j) { bb[j] = b2[j]; cs0[j] = cs2[j]; }
        }
        Q[i][tid] = r;                    // row i final
        r = Q[i + 1][tid];                // row i+1 was updated first this round
    }
    Q[NPTS - 1][tid] = r;
    __syncthreads();

#pragma unroll
    for (int row = 0; row < NPTS; ++row)
        Mout[row * NPTS + tid] = mus[row] * Q[row][tid];
}

// ---------------------------------------------------------------------------
// Kernel 2: out[64, NCOLS] = M[64,64] * X[64, NCOLS]  via bf16 MFMA.
// 64-column stripe per wave (exactly one stripe each), dwordx4 loads/stores.
// Column permutation trick: float4 element u of lane n feeds MFMA tile u at
// B-index n; output permutes identically so accumulators reassemble into a
// contiguous float4 store. Nontemporal stores keep `out` from evicting X.
// ---------------------------------------------------------------------------
__global__ __launch_bounds__(256) void apply_M(const float* __restrict__ X,
                                               const float* __restrict__ M,
                                               float* __restrict__ out,
                                               int nfull, int wstride) {
    const int lane  = threadIdx.x & 63;
    const int wave  = threadIdx.x >> 6;
    const int laneN = lane & 15;
    const int quad  = lane >> 4;

    // A fragments from M (fp32 -> bf16). A[m][k]: m = lane&15 (+16t),
    // k = quad*8 + j (+32q).   [verified correct]
    bf16x8 afrag[4][2];
#pragma unroll
    for (int t = 0; t < 4; ++t) {
#pragma unroll
        for (int q = 0; q < 2; ++q) {
            const float* src = M + (t * 16 + laneN) * NPTS + q * 32 + quad * 8;
            bf16x8 f;
#pragma unroll
            for (int j = 0; j < 8; ++j) f[j] = f2bf(src[j]);
            afrag[t][q] = f;
        }
    }

    const int gw = blockIdx.x * 4 + wave;

    for (int s = gw; s < nfull; s += wstride) {
        const long col0 = (long)s * 64 + 4 * laneN;
        const float* xb = X + col0;

        // B fragments for 4 tiles: tile u, B_u[k][n] = X[k][S + 4n + u]
        bf16x8 bfrag[4][2];
#pragma unroll
        for (int q = 0; q < 2; ++q) {
#pragma unroll
            for (int j = 0; j < 8; ++j) {
                const int kk = q * 32 + quad * 8 + j;
                f32x4 v = *(const f32x4*)(xb + (long)kk * NCOLS);
#pragma unroll
                for (int u = 0; u < 4; ++u)
                    bfrag[u][q][j] = f2bf(v[u]);
            }
        }

#pragma unroll
        for (int t = 0; t < 4; ++t) {
            f32x4 acc[4];
#pragma unroll
            for (int u = 0; u < 4; ++u) {
                f32x4 a = {0.f, 0.f, 0.f, 0.f};
                a = __builtin_amdgcn_mfma_f32_16x16x32_bf16(afrag[t][0], bfrag[u][0], a, 0, 0, 0);
                a = __builtin_amdgcn_mfma_f32_16x16x32_bf16(afrag[t][1], bfrag[u][1], a, 0, 0, 0);
                acc[u] = a;
            }
            // D: col = S + 4*laneN + u, row = t*16 + quad*4 + rr
#pragma unroll
            for (int rr = 0; rr < 4; ++rr) {
                const int row = t * 16 + quad * 4 + rr;
                f32x4 o = { acc[0][rr], acc[1][rr], acc[2][rr], acc[3][rr] };
                __builtin_nontemporal_store(o, (f32x4*)(out + (long)row * NCOLS + col0));
            }
        }
    }

    // Tail: NCOLS - nfull*64 = 32 columns, two 16-col stripes
    if (gw < 2) {
        const int col = nfull * 64 + gw * 16 + laneN;
        const float* xb = X + col;
        bf16x8 bfrag[2];
#pragma unroll
        for (int q = 0; q < 2; ++q) {
            bf16x8 f;
#pragma unroll
            for (int j = 0; j < 8; ++j)
                f[j] = f2bf(xb[(long)(q * 32 + quad * 8 + j) * NCOLS]);
            bfrag[q] = f;
        }
#pragma unroll
        for (int t = 0; t < 4; ++t) {
            f32x4 a = {0.f, 0.f, 0.f, 0.f};
            a = __builtin_amdgcn_mfma_f32_16x16x32_bf16(afrag[t][0], bfrag[0], a, 0, 0, 0);
            a = __builtin_amdgcn_mfma_f32_16x16x32_bf16(afrag[t][1], bfrag[1], a, 0, 0, 0);
#pragma unroll
            for (int rr = 0; rr < 4; ++rr)
                __builtin_nontemporal_store(a[rr],
                    out + (long)(t * 16 + quad * 4 + rr) * NCOLS + col);
        }
    }
}

extern "C" void kernel_launch(void* const* d_in, const int* in_sizes, int n_in,
                              void* d_out, int out_size, void* d_ws, size_t ws_size,
                              hipStream_t stream) {
    const float* X      = (const float*)d_in[0];
    const float* angles = (const float*)d_in[1];
    const float* mus    = (const float*)d_in[2];
    float* out = (float*)d_out;
    float* M   = (float*)d_ws;   // 64*64*4 = 16 KB scratch

    build_M<<<1, 64, 0, stream>>>(angles, mus, M);

    const int nfull  = NCOLS / 64;   // 7812 full 64-col stripes (+32 tail)
    const int blocks = 1953;         // 7812 waves -> exactly 1 stripe/wave
    apply_M<<<blocks, 256, 0, stream>>>(X, M, out, nfull, blocks * 4);
}

// Round 4
// 280.650 us; speedup vs baseline: 1.3465x; 1.3465x over previous
//
#include <hip/hip_runtime.h>
#include <hip/hip_bf16.h>

#define NPTS  64
#define NCOLS 500000
#define NANG  2016   // 64*63/2

typedef __attribute__((ext_vector_type(8))) short bf16x8;
typedef __attribute__((ext_vector_type(4))) float f32x4;

static __device__ inline short f2bf(float f) {
    union { float f; unsigned u; } uf; uf.f = f;
    unsigned u = uf.u;
    unsigned r = (u + 0x7fffu + ((u >> 16) & 1u)) >> 16;  // RNE bf16
    return (short)r;
}

// rotations before round i (iTop = i): S(i) = 63i - i(i-1)/2
static __host__ __device__ constexpr int rotS(int i) { return 63 * i - i * (i - 1) / 2; }

// ---------------------------------------------------------------------------
// Kernel 1: chunk partial products. Chunk = contiguous rounds [I0, I1) of the
// iTop loop. Thread = column; rows I0..63 live in REGISTERS with fully static
// indices (compile-time unroll); rows < I0 are untouched identity. Critical
// path = ~530 dependent FMAs, no LDS on the chain, ~3k instrs of code per
// chunk (no I-cache streaming).
// ---------------------------------------------------------------------------
template<int I0, int I1>
__device__ __forceinline__ void chunk_body(const float* __restrict__ angles,
                                           float* __restrict__ P,
                                           float2* csn) {
    constexpr int K0 = rotS(I0);
    constexpr int NK = rotS(I1) - K0;
    const int tid = threadIdx.x;

    for (int t = tid; t < NK; t += 64) {
        float s, c;
        sincosf(angles[K0 + t], &s, &c);
        csn[t] = make_float2(c, s);
    }
    __syncthreads();

    float q[64 - I0];
#pragma unroll
    for (int r = I0; r < 64; ++r) q[r - I0] = (r == tid) ? 1.0f : 0.0f;

    int k = 0;
#pragma unroll
    for (int i = I0; i < I1; ++i) {
#pragma unroll
        for (int ib = i + 1; ib < 64; ++ib, ++k) {
            float c = csn[k].x, s = csn[k].y;
            float t = q[i - I0], b = q[ib - I0];
            q[ib - I0] = s * t + c * b;   // both use OLD q[i] (matches ref)
            q[i - I0]  = c * t - s * b;
        }
        P[i * 64 + tid] = q[i - I0];      // row i final -> retire register
    }
#pragma unroll
    for (int r = 0; r < I0; ++r) P[r * 64 + tid] = (r == tid) ? 1.0f : 0.0f;
#pragma unroll
    for (int r = I1; r < 64; ++r) P[r * 64 + tid] = q[r - I0];
}

__global__ __launch_bounds__(64) void chunk_products(const float* __restrict__ angles,
                                                     float* __restrict__ ws) {
    __shared__ float2 csn[531];   // max chunk rotation count
    switch (blockIdx.x) {
        case 0: chunk_body< 0,  9>(angles, ws + 0 * 4096, csn); break;  // 531 rots
        case 1: chunk_body< 9, 19>(angles, ws + 1 * 4096, csn); break;  // 495
        case 2: chunk_body<19, 32>(angles, ws + 2 * 4096, csn); break;  // 494
        default: chunk_body<32, 63>(angles, ws + 3 * 4096, csn); break; // 496
    }
}

// ---------------------------------------------------------------------------
// Kernel 2: C = hi * lo (64x64 fp32). 256 threads: col = tid&63, wave rg owns
// rows rg*16..+15. hi reads are wave-uniform (rg via readfirstlane) ->
// s_load_dwordx4; lo reads coalesced. __syncthreads before stores because
// out may alias lo (level-1 writes in place). mus != null: scale rows (final).
// ---------------------------------------------------------------------------
__global__ __launch_bounds__(256) void combine(float* __restrict__ ws,
                                               int lo_off, int hi_off, int out_off,
                                               int blk_stride,
                                               const float* __restrict__ mus) {
    const float* lo = ws + lo_off  + blockIdx.x * blk_stride;
    const float* hi = ws + hi_off  + blockIdx.x * blk_stride;
    float*      co  = ws + out_off + blockIdx.x * blk_stride;
    const int col = threadIdx.x & 63;
    const int rg  = __builtin_amdgcn_readfirstlane(threadIdx.x >> 6);

    float acc[16] = {0.f};
#pragma unroll 4
    for (int k0 = 0; k0 < 64; k0 += 4) {
        float lo0 = lo[(k0 + 0) * 64 + col];
        float lo1 = lo[(k0 + 1) * 64 + col];
        float lo2 = lo[(k0 + 2) * 64 + col];
        float lo3 = lo[(k0 + 3) * 64 + col];
#pragma unroll
        for (int r = 0; r < 16; ++r) {
            f32x4 h = *(const f32x4*)(hi + (rg * 16 + r) * 64 + k0);  // s_load
            acc[r] = fmaf(h[0], lo0, acc[r]);
            acc[r] = fmaf(h[1], lo1, acc[r]);
            acc[r] = fmaf(h[2], lo2, acc[r]);
            acc[r] = fmaf(h[3], lo3, acc[r]);
        }
    }
    __syncthreads();   // all reads of lo done before in-place overwrite
#pragma unroll
    for (int r = 0; r < 16; ++r) {
        float v = acc[r];
        if (mus) v *= mus[rg * 16 + r];
        co[(rg * 16 + r) * 64 + col] = v;
    }
}

// ---------------------------------------------------------------------------
// Kernel 3: out[64, NCOLS] = M[64,64] * X[64, NCOLS] via bf16 MFMA.
// [unchanged proven structure: 64-col stripe/wave, dwordx4, permutation
// trick, nontemporal stores]
// ---------------------------------------------------------------------------
__global__ __launch_bounds__(256) void apply_M(const float* __restrict__ X,
                                               const float* __restrict__ M,
                                               float* __restrict__ out,
                                               int nfull, int wstride) {
    const int lane  = threadIdx.x & 63;
    const int wave  = threadIdx.x >> 6;
    const int laneN = lane & 15;
    const int quad  = lane >> 4;

    bf16x8 afrag[4][2];
#pragma unroll
    for (int t = 0; t < 4; ++t) {
#pragma unroll
        for (int q = 0; q < 2; ++q) {
            const float* src = M + (t * 16 + laneN) * NPTS + q * 32 + quad * 8;
            bf16x8 f;
#pragma unroll
            for (int j = 0; j < 8; ++j) f[j] = f2bf(src[j]);
            afrag[t][q] = f;
        }
    }

    const int gw = blockIdx.x * 4 + wave;

    for (int s = gw; s < nfull; s += wstride) {
        const long col0 = (long)s * 64 + 4 * laneN;
        const float* xb = X + col0;

        bf16x8 bfrag[4][2];
#pragma unroll
        for (int q = 0; q < 2; ++q) {
#pragma unroll
            for (int j = 0; j < 8; ++j) {
                const int kk = q * 32 + quad * 8 + j;
                f32x4 v = *(const f32x4*)(xb + (long)kk * NCOLS);
#pragma unroll
                for (int u = 0; u < 4; ++u)
                    bfrag[u][q][j] = f2bf(v[u]);
            }
        }

#pragma unroll
        for (int t = 0; t < 4; ++t) {
            f32x4 acc[4];
#pragma unroll
            for (int u = 0; u < 4; ++u) {
                f32x4 a = {0.f, 0.f, 0.f, 0.f};
                a = __builtin_amdgcn_mfma_f32_16x16x32_bf16(afrag[t][0], bfrag[u][0], a, 0, 0, 0);
                a = __builtin_amdgcn_mfma_f32_16x16x32_bf16(afrag[t][1], bfrag[u][1], a, 0, 0, 0);
                acc[u] = a;
            }
#pragma unroll
            for (int rr = 0; rr < 4; ++rr) {
                const int row = t * 16 + quad * 4 + rr;
                f32x4 o = { acc[0][rr], acc[1][rr], acc[2][rr], acc[3][rr] };
                __builtin_nontemporal_store(o, (f32x4*)(out + (long)row * NCOLS + col0));
            }
        }
    }

    if (gw < 2) {  // 32-col tail
        const int col = nfull * 64 + gw * 16 + laneN;
        const float* xb = X + col;
        bf16x8 bfrag[2];
#pragma unroll
        for (int q = 0; q < 2; ++q) {
            bf16x8 f;
#pragma unroll
            for (int j = 0; j < 8; ++j)
                f[j] = f2bf(xb[(long)(q * 32 + quad * 8 + j) * NCOLS]);
            bfrag[q] = f;
        }
#pragma unroll
        for (int t = 0; t < 4; ++t) {
            f32x4 a = {0.f, 0.f, 0.f, 0.f};
            a = __builtin_amdgcn_mfma_f32_16x16x32_bf16(afrag[t][0], bfrag[0], a, 0, 0, 0);
            a = __builtin_amdgcn_mfma_f32_16x16x32_bf16(afrag[t][1], bfrag[1], a, 0, 0, 0);
#pragma unroll
            for (int rr = 0; rr < 4; ++rr)
                __builtin_nontemporal_store(a[rr],
                    out + (long)(t * 16 + quad * 4 + rr) * NCOLS + col);
        }
    }
}

extern "C" void kernel_launch(void* const* d_in, const int* in_sizes, int n_in,
                              void* d_out, int out_size, void* d_ws, size_t ws_size,
                              hipStream_t stream) {
    const float* X      = (const float*)d_in[0];
    const float* angles = (const float*)d_in[1];
    const float* mus    = (const float*)d_in[2];
    float* out = (float*)d_out;
    float* wsf = (float*)d_ws;   // slots: P0 P1 P2 P3 (4096 floats each); 64KB

    // P_c = product of chunk c's rotations (chunk 0 applied first)
    chunk_products<<<4, 64, 0, stream>>>(angles, wsf);
    // Q0 = P1*P0 -> slot0 ; Q1 = P3*P2 -> slot2
    combine<<<2, 256, 0, stream>>>(wsf, 0, 4096, 0, 8192, nullptr);
    // M = diag(mus) * Q1*Q0 -> slot1
    combine<<<1, 256, 0, stream>>>(wsf, 0, 2 * 4096, 4096, 0, mus);

    const int nfull  = NCOLS / 64;   // 7812 stripes (+32-col tail)
    const int blocks = 1953;         // 7812 waves -> 1 stripe/wave
    apply_M<<<blocks, 256, 0, stream>>>(X, wsf + 4096, out, nfull, blocks * 4);
}